// Round 2
// baseline (805.225 us; speedup 1.0000x reference)
//
#include <hip/hip_runtime.h>
#include <hip/hip_bf16.h>
#include <stdint.h>

#define TOKENS 8192
#define DDIM 1024
#define HDIM 4096
#define NEXP 8
#define MAXENT 16384
#define MAXTILES 72
#define BT_ESTR ((size_t)DDIM * (size_t)HDIM)

typedef __attribute__((ext_vector_type(4))) float f32x4;
typedef __attribute__((ext_vector_type(8))) short bf16x8;
typedef __attribute__((ext_vector_type(4))) int i32x4;

__device__ __forceinline__ unsigned short f2bf(float f) {
  __hip_bfloat16 h = __float2bfloat16(f);
  return __builtin_bit_cast(unsigned short, h);
}

__device__ __forceinline__ void gload16(const void* g, void* l) {
  __builtin_amdgcn_global_load_lds(
      (const __attribute__((address_space(1))) unsigned int*)g,
      (__attribute__((address_space(3))) unsigned int*)l, 16, 0, 0);
}

__device__ __forceinline__ void bar() {
  asm volatile("" ::: "memory");
  __builtin_amdgcn_s_barrier();
  asm volatile("" ::: "memory");
}

#define VMWAIT(N) asm volatile("s_waitcnt vmcnt(" #N ")" ::: "memory")

// ---------------- prep: counts, offsets, tile list, scatter ----------------

__global__ void moe_count(const int* __restrict__ idx, int* __restrict__ meta) {
  int t = blockIdx.x * 256 + threadIdx.x;
  if (t >= TOKENS) return;
  int e0 = idx[2 * t], e1 = idx[2 * t + 1];
  atomicAdd(&meta[e0], 1);
  if (e1 != e0) atomicAdd(&meta[e1], 1);
}

__global__ void moe_scan(int* __restrict__ meta) {
  if (threadIdx.x != 0 || blockIdx.x != 0) return;
  int s = 0;
  for (int e = 0; e < NEXP; ++e) { meta[16 + e] = s; meta[32 + e] = s; s += meta[e]; }
  meta[16 + NEXP] = s;
  int nt = 0;
  for (int e = 0; e < NEXP; ++e) {
    int m = (meta[e] + 255) >> 8;
    for (int t = 0; t < m; ++t) meta[64 + nt++] = e | (t << 8);
  }
  meta[48] = nt;
}

__global__ void moe_scatter(const int* __restrict__ idx, const float* __restrict__ ew,
                            int* __restrict__ meta, int* __restrict__ etok,
                            float* __restrict__ ewgt) {
  int t = blockIdx.x * 256 + threadIdx.x;
  if (t >= TOKENS) return;
  int e0 = idx[2 * t], e1 = idx[2 * t + 1];
  float a = ew[2 * t], b = ew[2 * t + 1];
  if (e0 == e1) {
    int p = atomicAdd(&meta[32 + e0], 1);
    etok[p] = t; ewgt[p] = a + b;
  } else {
    int p = atomicAdd(&meta[32 + e0], 1);
    etok[p] = t; ewgt[p] = a;
    int q = atomicAdd(&meta[32 + e1], 1);
    etok[q] = t; ewgt[q] = b;
  }
}

// ---------------- conversions ----------------

__global__ void cvt_x_bf16(const float* __restrict__ src, unsigned short* __restrict__ dst, int n8) {
  int i = blockIdx.x * 256 + threadIdx.x;
  if (i >= n8) return;
  const float4* s4 = (const float4*)src;
  float4 a = s4[2 * i], b = s4[2 * i + 1];
  union { unsigned short h[8]; i32x4 v; } o;
  o.h[0] = f2bf(a.x); o.h[1] = f2bf(a.y); o.h[2] = f2bf(a.z); o.h[3] = f2bf(a.w);
  o.h[4] = f2bf(b.x); o.h[5] = f2bf(b.y); o.h[6] = f2bf(b.z); o.h[7] = f2bf(b.w);
  ((i32x4*)dst)[i] = o.v;
}

// src [E][R][C] fp32 -> dst [E][C][R] bf16, packed ushort2 stores
__global__ void trans_cvt(const float* __restrict__ src, unsigned short* __restrict__ dst,
                          int R, int C) {
  __shared__ float tile[64][33];
  int e = blockIdx.z;
  const float* s = src + (size_t)e * R * C;
  unsigned short* d = dst + (size_t)e * R * C;
  int c0 = blockIdx.x * 32, r0 = blockIdx.y * 64;
  int tx = threadIdx.x, ty = threadIdx.y;
  int tid = ty * 32 + tx;
  for (int i = ty; i < 64; i += 8)
    tile[i][tx] = s[(size_t)(r0 + i) * C + c0 + tx];
  __syncthreads();
#pragma unroll
  for (int it = 0; it < 4; ++it) {
    int unit = it * 256 + tid;
    int j = unit >> 5, p = unit & 31;
    unsigned int lo = f2bf(tile[2 * p][j]);
    unsigned int hi = f2bf(tile[2 * p + 1][j]);
    *(unsigned int*)(d + (size_t)(c0 + j) * R + r0 + 2 * p) = lo | (hi << 16);
  }
}

// ---------------- GEMM: 256x256 tile, BK=32, 8 waves, 4-deep ring, counted vmcnt ----
// MODE 0: x@w1 -> silu -> h ;  MODE 1: h@w2 -> atomic out

template <int MODE>
__global__ __launch_bounds__(512, 2) void moe_gemm(
    const unsigned short* __restrict__ Abase,   // x_bf16 [TOKENS][DDIM] or h [MAXENT][HC]
    const unsigned short* __restrict__ Btbase,  // [E][N][K] bf16 (transposed weights)
    const float* __restrict__ bias,
    const int* __restrict__ meta,
    const int* __restrict__ etok,
    const float* __restrict__ ewgt,
    unsigned short* __restrict__ Hbuf,
    float* __restrict__ Out,
    int Astride, int BtRowStride,
    int nbase, int kbase, int Klen,
    int biasStride, int Hstride, int addbias) {
  const int* offsets = meta + 16;
  int ntiles = meta[48];
  if ((int)blockIdx.y >= ntiles) return;
  int te = meta[64 + blockIdx.y];
  int e = te & 255, mt = te >> 8;
  int off = offsets[e], cnt = offsets[e + 1] - off;
  if (mt * 256 >= cnt) return;
  int nt = blockIdx.x;
  int total = offsets[NEXP];

  // 4-slot ring: each slot 256 rows x 32 bf16 = 16 KiB per matrix
  __shared__ unsigned short As[4 * 8192];
  __shared__ unsigned short Bs[4 * 8192];

  int tid = threadIdx.x;
  int lane = tid & 63, wid = tid >> 6;
  int wr = wid >> 2, wc = wid & 3;
  int fr = lane & 15, fu = lane >> 4;
  int su16 = (fu ^ (fr & 3)) * 16;

  // staging: thread handles units v0=tid (row r0), v1=512+tid (row r0+128)
  int r0 = tid >> 2, u0 = tid & 3;
  int usw = (u0 ^ (r0 & 3)) * 16;  // (r0+128)&3 == r0&3

  const unsigned short* BtE = Btbase + (size_t)e * BT_ESTR + (size_t)nbase * BtRowStride + kbase;
  const char* srcB0 = (const char*)(BtE + (size_t)(nt * 256 + r0) * BtRowStride) + usw;
  const char* srcB1 = (const char*)(BtE + (size_t)(nt * 256 + r0 + 128) * BtRowStride) + usw;

  const char* srcA0;
  const char* srcA1;
  {
    int gi0 = off + mt * 256 + r0;
    int gi1 = gi0 + 128;
    if (gi0 > total - 1) gi0 = total - 1;
    if (gi1 > total - 1) gi1 = total - 1;
    if (MODE == 0) {
      srcA0 = (const char*)(Abase + (size_t)etok[gi0] * Astride) + usw;
      srcA1 = (const char*)(Abase + (size_t)etok[gi1] * Astride) + usw;
    } else {
      srcA0 = (const char*)(Abase + (size_t)gi0 * Astride) + usw;
      srcA1 = (const char*)(Abase + (size_t)gi1 * Astride) + usw;
    }
  }

#define STAGE_A(Tn) do { \
    char* _b = (char*)As + (((Tn) & 3) * 16384); \
    size_t _ko = (size_t)(Tn) * 64; \
    gload16(srcA0 + _ko, _b + wid * 1024); \
    gload16(srcA1 + _ko, _b + 8192 + wid * 1024); } while (0)
#define STAGE_B(Tn) do { \
    char* _b = (char*)Bs + (((Tn) & 3) * 16384); \
    size_t _ko = (size_t)(Tn) * 64; \
    gload16(srcB0 + _ko, _b + wid * 1024); \
    gload16(srcB1 + _ko, _b + 8192 + wid * 1024); } while (0)

  f32x4 acc[8][4];
#pragma unroll
  for (int m = 0; m < 8; ++m)
#pragma unroll
    for (int n = 0; n < 4; ++n) acc[m][n] = (f32x4){0.f, 0.f, 0.f, 0.f};

  int nk = Klen >> 5;  // K-tiles of 32 (nk >= 32 always here)

  // prologue: stage tiles 0,1,2
  STAGE_A(0); STAGE_B(0);
  STAGE_A(1); STAGE_B(1);
  STAGE_A(2); STAGE_B(2);
  VMWAIT(8);  // tile 0 landed
  bar();

  for (int T = 0; T < nk; ++T) {
    const char* sA = (const char*)As + ((T & 3) * 16384);
    const char* sB = (const char*)Bs + ((T & 3) * 16384);
    const char* rbase = sA + (size_t)(wr * 128 + fr) * 64 + su16;
    const char* nbp = sB + (size_t)(wc * 64 + fr) * 64 + su16;

    // ---- phase A: issue A-stage of T+3, compute m-half 0 ----
    if (T + 3 < nk) STAGE_A(T + 3);
    bf16x8 af[4], bg[4];
#pragma unroll
    for (int m = 0; m < 4; ++m) af[m] = *(const bf16x8*)(rbase + m * 1024);
#pragma unroll
    for (int n = 0; n < 4; ++n) bg[n] = *(const bf16x8*)(nbp + n * 1024);
    __builtin_amdgcn_s_setprio(1);
#pragma unroll
    for (int m = 0; m < 4; ++m)
#pragma unroll
      for (int n = 0; n < 4; ++n)
        acc[m][n] = __builtin_amdgcn_mfma_f32_16x16x32_bf16(af[m], bg[n], acc[m][n], 0, 0, 0);
    __builtin_amdgcn_s_setprio(0);
    bar();

    // ---- phase B: issue B-stage of T+3, compute m-half 1 ----
    if (T + 3 < nk) STAGE_B(T + 3);
#pragma unroll
    for (int m = 0; m < 4; ++m) af[m] = *(const bf16x8*)(rbase + (64 + m * 16) * 64);
    __builtin_amdgcn_s_setprio(1);
#pragma unroll
    for (int m = 0; m < 4; ++m)
#pragma unroll
      for (int n = 0; n < 4; ++n)
        acc[m + 4][n] = __builtin_amdgcn_mfma_f32_16x16x32_bf16(af[m], bg[n], acc[m + 4][n], 0, 0, 0);
    __builtin_amdgcn_s_setprio(0);

    // counted drain: ensure tile T+1 landed; keep the rest in flight
    if (T + 3 < nk)      { VMWAIT(8); }
    else if (T + 2 < nk) { VMWAIT(4); }
    else if (T + 1 < nk) { VMWAIT(0); }
    bar();
  }
#undef STAGE_A
#undef STAGE_B

  int colb = nt * 256 + wc * 64;
  if (MODE == 0) {
#pragma unroll
    for (int m = 0; m < 8; ++m) {
#pragma unroll
      for (int r = 0; r < 4; ++r) {
        int row = wr * 128 + m * 16 + fu * 4 + r;
        int gm = mt * 256 + row;
        if (gm < cnt) {
          size_t hrow = (size_t)(off + gm) * Hstride;
#pragma unroll
          for (int n = 0; n < 4; ++n) {
            int col = colb + n * 16 + fr;
            float v = acc[m][n][r] + bias[e * biasStride + nbase + col];
            v = v / (1.f + __expf(-v));
            Hbuf[hrow + col] = f2bf(v);
          }
        }
      }
    }
  } else {
#pragma unroll
    for (int m = 0; m < 8; ++m) {
#pragma unroll
      for (int r = 0; r < 4; ++r) {
        int row = wr * 128 + m * 16 + fu * 4 + r;
        int gm = mt * 256 + row;
        if (gm < cnt) {
          int ent = off + gm;
          int tok = etok[ent];
          float wgt = ewgt[ent];
#pragma unroll
          for (int n = 0; n < 4; ++n) {
            int col = colb + n * 16 + fr;
            float v = acc[m][n][r];
            if (addbias) v += bias[e * biasStride + col];
            atomicAdd(Out + (size_t)tok * DDIM + col, v * wgt);
          }
        }
      }
    }
  }
}

// ---------------- host launch ----------------

extern "C" void kernel_launch(void* const* d_in, const int* in_sizes, int n_in,
                              void* d_out, int out_size, void* d_ws, size_t ws_size,
                              hipStream_t stream) {
  (void)in_sizes; (void)n_in;
  const float* x = (const float*)d_in[0];
  const int* eidx = (const int*)d_in[1];
  const float* ew = (const float*)d_in[2];
  const float* w1 = (const float*)d_in[3];
  const float* b1 = (const float*)d_in[4];
  const float* w2 = (const float*)d_in[5];
  const float* b2 = (const float*)d_in[6];
  float* out = (float*)d_out;

  char* w = (char*)d_ws;
  size_t o_meta = 0;
  size_t o_etok = 4096;
  size_t o_ewgt = o_etok + (size_t)MAXENT * 4;
  size_t o_x    = o_ewgt + (size_t)MAXENT * 4;
  size_t o_w1t  = o_x + (size_t)TOKENS * DDIM * 2;
  size_t o_w2t  = o_w1t + (size_t)NEXP * BT_ESTR * 2;
  size_t o_h    = o_w2t + (size_t)NEXP * BT_ESTR * 2;

  int S = 1;
  while (S < 16) {
    size_t need = o_h + (size_t)MAXENT * (HDIM / S) * 2;
    if (need <= ws_size) break;
    S *= 2;
  }
  int HC = HDIM / S;

  int* meta = (int*)(w + o_meta);
  int* etok = (int*)(w + o_etok);
  float* ewgt = (float*)(w + o_ewgt);
  unsigned short* xb = (unsigned short*)(w + o_x);
  unsigned short* w1t = (unsigned short*)(w + o_w1t);
  unsigned short* w2t = (unsigned short*)(w + o_w2t);
  unsigned short* hbuf = (unsigned short*)(w + o_h);

  hipMemsetAsync(w + o_meta, 0, 4096, stream);
  hipMemsetAsync(d_out, 0, (size_t)out_size * 4, stream);

  moe_count<<<TOKENS / 256, 256, 0, stream>>>(eidx, meta);
  moe_scan<<<1, 64, 0, stream>>>(meta);
  moe_scatter<<<TOKENS / 256, 256, 0, stream>>>(eidx, ew, meta, etok, ewgt);
  cvt_x_bf16<<<(TOKENS * DDIM / 8 + 255) / 256, 256, 0, stream>>>(x, xb, TOKENS * DDIM / 8);
  trans_cvt<<<dim3(HDIM / 32, DDIM / 64, NEXP), dim3(32, 8), 0, stream>>>(w1, w1t, DDIM, HDIM);
  trans_cvt<<<dim3(DDIM / 32, HDIM / 64, NEXP), dim3(32, 8), 0, stream>>>(w2, w2t, HDIM, DDIM);

  for (int s = 0; s < S; ++s) {
    moe_gemm<0><<<dim3(HC / 256, MAXTILES, 1), 512, 0, stream>>>(
        xb, w1t, b1, meta, etok, ewgt, hbuf, nullptr,
        DDIM, DDIM, s * HC, 0, DDIM, HDIM, HC, 0);
    moe_gemm<1><<<dim3(DDIM / 256, MAXTILES, 1), 512, 0, stream>>>(
        hbuf, w2t, b2, meta, etok, ewgt, nullptr, out,
        HC, HDIM, 0, s * HC, HC, DDIM, 0, (s == 0) ? 1 : 0);
  }
}

// Round 3
// 605.947 us; speedup vs baseline: 1.3289x; 1.3289x over previous
//
#include <hip/hip_runtime.h>
#include <hip/hip_bf16.h>
#include <stdint.h>

#define TOKENS 8192
#define DDIM 1024
#define HDIM 4096
#define NEXP 8
#define MAXENT 16384
#define MAXTILES 72
#define BT_ESTR ((size_t)DDIM * (size_t)HDIM)

typedef __attribute__((ext_vector_type(4))) float f32x4;
typedef __attribute__((ext_vector_type(8))) short bf16x8;
typedef __attribute__((ext_vector_type(4))) int i32x4;

__device__ __forceinline__ unsigned short f2bf(float f) {
  __hip_bfloat16 h = __float2bfloat16(f);
  return __builtin_bit_cast(unsigned short, h);
}

__device__ __forceinline__ void gload16(const void* g, void* l) {
  __builtin_amdgcn_global_load_lds(
      (const __attribute__((address_space(1))) unsigned int*)g,
      (__attribute__((address_space(3))) unsigned int*)l, 16, 0, 0);
}

__device__ __forceinline__ void bar() {
  asm volatile("" ::: "memory");
  __builtin_amdgcn_s_barrier();
  asm volatile("" ::: "memory");
}

#define VMWAIT(N) asm volatile("s_waitcnt vmcnt(" #N ")" ::: "memory")

// ---------------- prep ----------------

__global__ void moe_count(const int* __restrict__ idx, int* __restrict__ meta) {
  int t = blockIdx.x * 256 + threadIdx.x;
  if (t >= TOKENS) return;
  int e0 = idx[2 * t], e1 = idx[2 * t + 1];
  atomicAdd(&meta[e0], 1);
  if (e1 != e0) atomicAdd(&meta[e1], 1);
}

__global__ void moe_scan(int* __restrict__ meta) {
  if (threadIdx.x != 0 || blockIdx.x != 0) return;
  int s = 0;
  for (int e = 0; e < NEXP; ++e) { meta[16 + e] = s; meta[32 + e] = s; s += meta[e]; }
  meta[16 + NEXP] = s;
  int nt = 0;
  for (int e = 0; e < NEXP; ++e) {
    int m = (meta[e] + 255) >> 8;
    for (int t = 0; t < m; ++t) meta[64 + nt++] = e | (t << 8);
  }
  meta[48] = nt;
}

__global__ void moe_scatter(const int* __restrict__ idx, const float* __restrict__ ew,
                            int* __restrict__ meta, int* __restrict__ etok,
                            float* __restrict__ ewgt) {
  int t = blockIdx.x * 256 + threadIdx.x;
  if (t >= TOKENS) return;
  int e0 = idx[2 * t], e1 = idx[2 * t + 1];
  float a = ew[2 * t], b = ew[2 * t + 1];
  if (e0 == e1) {
    int p = atomicAdd(&meta[32 + e0], 1);
    etok[p] = t; ewgt[p] = a + b;
  } else {
    int p = atomicAdd(&meta[32 + e0], 1);
    etok[p] = t; ewgt[p] = a;
    int q = atomicAdd(&meta[32 + e1], 1);
    etok[q] = t; ewgt[q] = b;
  }
}

// ---------------- conversions ----------------

__global__ void cvt_x_bf16(const float* __restrict__ src, unsigned short* __restrict__ dst, int n8) {
  int i = blockIdx.x * 256 + threadIdx.x;
  if (i >= n8) return;
  const float4* s4 = (const float4*)src;
  float4 a = s4[2 * i], b = s4[2 * i + 1];
  union { unsigned short h[8]; i32x4 v; } o;
  o.h[0] = f2bf(a.x); o.h[1] = f2bf(a.y); o.h[2] = f2bf(a.z); o.h[3] = f2bf(a.w);
  o.h[4] = f2bf(b.x); o.h[5] = f2bf(b.y); o.h[6] = f2bf(b.z); o.h[7] = f2bf(b.w);
  ((i32x4*)dst)[i] = o.v;
}

// src [E][R][C] fp32 -> dst [E][C][R] bf16
__global__ void trans_cvt(const float* __restrict__ src, unsigned short* __restrict__ dst,
                          int R, int C) {
  __shared__ float tile[64][33];
  int e = blockIdx.z;
  const float* s = src + (size_t)e * R * C;
  unsigned short* d = dst + (size_t)e * R * C;
  int c0 = blockIdx.x * 32, r0 = blockIdx.y * 64;
  int tx = threadIdx.x, ty = threadIdx.y;
  int tid = ty * 32 + tx;
  for (int i = ty; i < 64; i += 8)
    tile[i][tx] = s[(size_t)(r0 + i) * C + c0 + tx];
  __syncthreads();
#pragma unroll
  for (int it = 0; it < 4; ++it) {
    int unit = it * 256 + tid;
    int j = unit >> 5, p = unit & 31;
    unsigned int lo = f2bf(tile[2 * p][j]);
    unsigned int hi = f2bf(tile[2 * p + 1][j]);
    *(unsigned int*)(d + (size_t)(c0 + j) * R + r0 + 2 * p) = lo | (hi << 16);
  }
}

// ---------------- GEMM: 256x256, BK=64, 8 waves, half-slot ring, counted vmcnt ----
// Conflict-free LDS: 128B rows, unit swizzle u ^= (row&7). XCD-chunked block remap.

template <int M0>
__device__ __forceinline__ void phase_run(f32x4 (&acc)[8][4], const char* pa0, const char* pa1,
                                          const bf16x8 (&bg0)[4], const bf16x8 (&bg1)[4]) {
  bf16x8 a00 = *(const bf16x8*)(pa0 + M0 * 2048);
  bf16x8 a01 = *(const bf16x8*)(pa1 + M0 * 2048);
  bf16x8 a10 = *(const bf16x8*)(pa0 + (M0 + 1) * 2048);
  bf16x8 a11 = *(const bf16x8*)(pa1 + (M0 + 1) * 2048);
  __builtin_amdgcn_s_setprio(1);
#pragma unroll
  for (int n = 0; n < 4; ++n) {
    acc[M0][n]     = __builtin_amdgcn_mfma_f32_16x16x32_bf16(a00, bg0[n], acc[M0][n], 0, 0, 0);
    acc[M0][n]     = __builtin_amdgcn_mfma_f32_16x16x32_bf16(a01, bg1[n], acc[M0][n], 0, 0, 0);
    acc[M0 + 1][n] = __builtin_amdgcn_mfma_f32_16x16x32_bf16(a10, bg0[n], acc[M0 + 1][n], 0, 0, 0);
    acc[M0 + 1][n] = __builtin_amdgcn_mfma_f32_16x16x32_bf16(a11, bg1[n], acc[M0 + 1][n], 0, 0, 0);
  }
  __builtin_amdgcn_s_setprio(0);
}

template <int MODE>
__global__ __launch_bounds__(512, 2) void moe_gemm(
    const unsigned short* __restrict__ Abase,
    const unsigned short* __restrict__ Btbase,
    const float* __restrict__ bias,
    const int* __restrict__ meta,
    const int* __restrict__ etok,
    const float* __restrict__ ewgt,
    unsigned short* __restrict__ Hbuf,
    float* __restrict__ Out,
    int Astride, int BtRowStride,
    int nbase, int kbase, int Klen,
    int biasStride, int Hstride, int addbias) {
  const int* offsets = meta + 16;
  int ntiles = meta[48];
  int NX = gridDim.x;
  int lid = blockIdx.x + NX * blockIdx.y;
  int Ntot = NX * ntiles;
  if (lid >= Ntot) return;
  // bijective XCD-chunked remap: each XCD owns a contiguous range of (nt, mtile)
  // with m fastest -> per-XCD B panel stays L2-resident.
  int q = Ntot >> 3, r = Ntot & 7;
  int xcd = lid & 7, pos = lid >> 3;
  int nlid = (xcd < r ? xcd * (q + 1) : r * (q + 1) + (xcd - r) * q) + pos;
  int nt = nlid / ntiles;
  int mti = nlid - nt * ntiles;
  int te = meta[64 + mti];
  int e = te & 255, mt = te >> 8;
  int off = offsets[e], cnt = offsets[e + 1] - off;
  int total = offsets[NEXP];

  // half-slot ring: 4 A-slots + 4 B-slots, each 128 rows x 128 B = 16 KiB
  __shared__ __align__(128) char lds[131072];

  int tid = threadIdx.x;
  int lane = tid & 63, wid = tid >> 6;
  int wr = wid >> 2, wc = wid & 3;
  int fr = lane & 15, fu = lane >> 4;
  int cu0 = fu ^ (fr & 7);
  int cu1 = cu0 ^ 4;
  int bro = (wc & 1) * 64 + fr;

  // staging source pointers: lane covers (row = wid*16 + j*8 + (lane>>3), unit = lane&7)
  int rg = (lane >> 3) & 7;
  int g = (lane & 7) ^ rg;  // pre-swizzled source unit
  const char* srcA[2][2];
  const char* srcB[2][2];
  const unsigned short* BtE = Btbase + (size_t)e * BT_ESTR + (size_t)nbase * BtRowStride + kbase;
#pragma unroll
  for (int h = 0; h < 2; ++h) {
#pragma unroll
    for (int j = 0; j < 2; ++j) {
      int rA = wid * 16 + j * 8 + rg;  // row within half (0..127)
      srcB[h][j] = (const char*)(BtE + (size_t)(nt * 256 + h * 128 + rA) * BtRowStride) + g * 16;
      int gi = off + mt * 256 + h * 128 + rA;
      if (MODE == 0) {
        if (gi > total - 1) gi = total - 1;
        srcA[h][j] = (const char*)(Abase + (size_t)etok[gi] * Astride) + g * 16;
      } else {
        if (gi > MAXENT - 1) gi = MAXENT - 1;
        srcA[h][j] = (const char*)(Abase + (size_t)gi * Astride) + g * 16;
      }
    }
  }

#define STA(Tn, h) do { \
    char* _d = lds + (((2 * (Tn) + (h)) & 3) << 14) + wid * 2048; \
    gload16(srcA[h][0] + ((size_t)(Tn) << 7), _d); \
    gload16(srcA[h][1] + ((size_t)(Tn) << 7), _d + 1024); } while (0)
#define STB(Tn, h) do { \
    char* _d = lds + 65536 + (((2 * (Tn) + (h)) & 3) << 14) + wid * 2048; \
    gload16(srcB[h][0] + ((size_t)(Tn) << 7), _d); \
    gload16(srcB[h][1] + ((size_t)(Tn) << 7), _d + 1024); } while (0)

  f32x4 acc[8][4];
#pragma unroll
  for (int m = 0; m < 8; ++m)
#pragma unroll
    for (int n = 0; n < 4; ++n) acc[m][n] = (f32x4){0.f, 0.f, 0.f, 0.f};

  int nk = Klen >> 6;  // K-tiles of 64 (nk >= 16 here)

  // prologue: A(0), B(0), B(1) staged; A(1) gets staged during T=0 per steady pattern
  STA(0, 0); STA(0, 1); STB(0, 0); STB(0, 1); STB(1, 0); STB(1, 1);
  VMWAIT(4);  // tile 0 fully landed; B(1) (4 loads) still in flight
  bar();

  for (int T = 0; T < nk; ++T) {
    const char* sA = lds + (((2 * T + wr) & 3) << 14);
    const char* sB = lds + 65536 + (((2 * T + (wc >> 1)) & 3) << 14);
    const char* pa0 = sA + fr * 128 + cu0 * 16;
    const char* pa1 = sA + fr * 128 + cu1 * 16;
    const char* pb0 = sB + bro * 128 + cu0 * 16;
    const char* pb1 = sB + bro * 128 + cu1 * 16;
    bool s1 = (T + 1 < nk), s2 = (T + 2 < nk);

    // phase 0: read all B-frags + A m0,m1; stage A-half0(T+1)
    bf16x8 bg0[4], bg1[4];
#pragma unroll
    for (int n = 0; n < 4; ++n) {
      bg0[n] = *(const bf16x8*)(pb0 + n * 2048);
      bg1[n] = *(const bf16x8*)(pb1 + n * 2048);
    }
    if (s1) STA(T + 1, 0);
    phase_run<0>(acc, pa0, pa1, bg0, bg1);
    bar();

    // phase 1: A m2,m3; stage A-half1(T+1)
    if (s1) STA(T + 1, 1);
    phase_run<2>(acc, pa0, pa1, bg0, bg1);
    bar();

    // phase 2: A m4,m5; stage B-half0(T+2)
    if (s2) STB(T + 2, 0);
    phase_run<4>(acc, pa0, pa1, bg0, bg1);
    bar();

    // phase 3: A m6,m7; stage B-half1(T+2); counted drain
    if (s2) STB(T + 2, 1);
    phase_run<6>(acc, pa0, pa1, bg0, bg1);
    if (s2) { VMWAIT(4); }
    else if (s1) { VMWAIT(0); }
    bar();
  }
#undef STA
#undef STB

  int colb = nt * 256 + wc * 64;
  if (MODE == 0) {
#pragma unroll
    for (int m = 0; m < 8; ++m) {
#pragma unroll
      for (int r = 0; r < 4; ++r) {
        int row = wr * 128 + m * 16 + fu * 4 + r;
        int gm = mt * 256 + row;
        if (gm < cnt) {
          size_t hrow = (size_t)(off + gm) * Hstride;
#pragma unroll
          for (int n = 0; n < 4; ++n) {
            int col = colb + n * 16 + fr;
            float v = acc[m][n][r] + bias[e * biasStride + nbase + col];
            v = v / (1.f + __expf(-v));
            Hbuf[hrow + col] = f2bf(v);
          }
        }
      }
    }
  } else {
#pragma unroll
    for (int m = 0; m < 8; ++m) {
#pragma unroll
      for (int r = 0; r < 4; ++r) {
        int row = wr * 128 + m * 16 + fu * 4 + r;
        int gm = mt * 256 + row;
        if (gm < cnt) {
          int ent = off + gm;
          int tok = etok[ent];
          float wgt = ewgt[ent];
#pragma unroll
          for (int n = 0; n < 4; ++n) {
            int col = colb + n * 16 + fr;
            float v = acc[m][n][r];
            if (addbias) v += bias[e * biasStride + col];
            atomicAdd(Out + (size_t)tok * DDIM + col, v * wgt);
          }
        }
      }
    }
  }
}

// ---------------- host launch ----------------

extern "C" void kernel_launch(void* const* d_in, const int* in_sizes, int n_in,
                              void* d_out, int out_size, void* d_ws, size_t ws_size,
                              hipStream_t stream) {
  (void)in_sizes; (void)n_in;
  const float* x = (const float*)d_in[0];
  const int* eidx = (const int*)d_in[1];
  const float* ew = (const float*)d_in[2];
  const float* w1 = (const float*)d_in[3];
  const float* b1 = (const float*)d_in[4];
  const float* w2 = (const float*)d_in[5];
  const float* b2 = (const float*)d_in[6];
  float* out = (float*)d_out;

  char* w = (char*)d_ws;
  size_t o_meta = 0;
  size_t o_etok = 4096;
  size_t o_ewgt = o_etok + (size_t)MAXENT * 4;
  size_t o_x    = o_ewgt + (size_t)MAXENT * 4;
  size_t o_w1t  = o_x + (size_t)TOKENS * DDIM * 2;
  size_t o_w2t  = o_w1t + (size_t)NEXP * BT_ESTR * 2;
  size_t o_h    = o_w2t + (size_t)NEXP * BT_ESTR * 2;

  int S = 1;
  while (S < 16) {
    size_t need = o_h + (size_t)MAXENT * (HDIM / S) * 2;
    if (need <= ws_size) break;
    S *= 2;
  }
  int HC = HDIM / S;

  int* meta = (int*)(w + o_meta);
  int* etok = (int*)(w + o_etok);
  float* ewgt = (float*)(w + o_ewgt);
  unsigned short* xb = (unsigned short*)(w + o_x);
  unsigned short* w1t = (unsigned short*)(w + o_w1t);
  unsigned short* w2t = (unsigned short*)(w + o_w2t);
  unsigned short* hbuf = (unsigned short*)(w + o_h);

  hipMemsetAsync(w + o_meta, 0, 4096, stream);
  hipMemsetAsync(d_out, 0, (size_t)out_size * 4, stream);

  moe_count<<<TOKENS / 256, 256, 0, stream>>>(eidx, meta);
  moe_scan<<<1, 64, 0, stream>>>(meta);
  moe_scatter<<<TOKENS / 256, 256, 0, stream>>>(eidx, ew, meta, etok, ewgt);
  cvt_x_bf16<<<(TOKENS * DDIM / 8 + 255) / 256, 256, 0, stream>>>(x, xb, TOKENS * DDIM / 8);
  trans_cvt<<<dim3(HDIM / 32, DDIM / 64, NEXP), dim3(32, 8), 0, stream>>>(w1, w1t, DDIM, HDIM);
  trans_cvt<<<dim3(DDIM / 32, HDIM / 64, NEXP), dim3(32, 8), 0, stream>>>(w2, w2t, HDIM, DDIM);

  for (int s = 0; s < S; ++s) {
    moe_gemm<0><<<dim3(HC / 256, MAXTILES, 1), 512, 0, stream>>>(
        xb, w1t, b1, meta, etok, ewgt, hbuf, nullptr,
        DDIM, DDIM, s * HC, 0, DDIM, HDIM, HC, 0);
    moe_gemm<1><<<dim3(DDIM / 256, MAXTILES, 1), 512, 0, stream>>>(
        hbuf, w2t, b2, meta, etok, ewgt, nullptr, out,
        HC, HDIM, 0, s * HC, HC, DDIM, 0, (s == 0) ? 1 : 0);
  }
}

// Round 4
// 591.191 us; speedup vs baseline: 1.3620x; 1.0250x over previous
//
#include <hip/hip_runtime.h>
#include <hip/hip_bf16.h>
#include <stdint.h>

#define TOKENS 8192
#define DDIM 1024
#define HDIM 4096
#define NEXP 8
#define MAXENT 16384
#define MAXTILES 72

typedef __attribute__((ext_vector_type(4))) float f32x4;
typedef __attribute__((ext_vector_type(8))) short bf16x8;
typedef __attribute__((ext_vector_type(4))) int i32x4;

__device__ __forceinline__ unsigned short f2bf(float f) {
  __hip_bfloat16 h = __float2bfloat16(f);
  return __builtin_bit_cast(unsigned short, h);
}

__device__ __forceinline__ void gload16(const void* g, void* l) {
  __builtin_amdgcn_global_load_lds(
      (const __attribute__((address_space(1))) unsigned int*)g,
      (__attribute__((address_space(3))) unsigned int*)l, 16, 0, 0);
}

__device__ __forceinline__ void bar() {
  asm volatile("" ::: "memory");
  __builtin_amdgcn_sched_barrier(0);
  __builtin_amdgcn_s_barrier();
  __builtin_amdgcn_sched_barrier(0);
  asm volatile("" ::: "memory");
}

#define VMWAIT(N) asm volatile("s_waitcnt vmcnt(" #N ")" ::: "memory")

// ---------------- prep ----------------

__global__ void moe_count(const int* __restrict__ idx, int* __restrict__ meta) {
  int t = blockIdx.x * 256 + threadIdx.x;
  if (t >= TOKENS) return;
  int e0 = idx[2 * t], e1 = idx[2 * t + 1];
  atomicAdd(&meta[e0], 1);
  if (e1 != e0) atomicAdd(&meta[e1], 1);
}

__global__ void moe_scan(int* __restrict__ meta) {
  if (threadIdx.x != 0 || blockIdx.x != 0) return;
  int s = 0;
  for (int e = 0; e < NEXP; ++e) { meta[16 + e] = s; meta[32 + e] = s; s += meta[e]; }
  meta[16 + NEXP] = s;
  int nt = 0;
  for (int e = 0; e < NEXP; ++e) {
    int m = (meta[e] + 255) >> 8;
    for (int t = 0; t < m; ++t) meta[64 + nt++] = e | (t << 8);
  }
  meta[48] = nt;
}

__global__ void moe_scatter(const int* __restrict__ idx, const float* __restrict__ ew,
                            int* __restrict__ meta, int* __restrict__ etok,
                            float* __restrict__ ewgt) {
  int t = blockIdx.x * 256 + threadIdx.x;
  if (t >= TOKENS) return;
  int e0 = idx[2 * t], e1 = idx[2 * t + 1];
  float a = ew[2 * t], b = ew[2 * t + 1];
  if (e0 == e1) {
    int p = atomicAdd(&meta[32 + e0], 1);
    etok[p] = t; ewgt[p] = a + b;
  } else {
    int p = atomicAdd(&meta[32 + e0], 1);
    etok[p] = t; ewgt[p] = a;
    int q = atomicAdd(&meta[32 + e1], 1);
    etok[q] = t; ewgt[q] = b;
  }
}

// ---------------- conversions ----------------

__global__ void cvt_x_bf16(const float* __restrict__ src, unsigned short* __restrict__ dst, int n8) {
  int i = blockIdx.x * 256 + threadIdx.x;
  if (i >= n8) return;
  const float4* s4 = (const float4*)src;
  float4 a = s4[2 * i], b = s4[2 * i + 1];
  union { unsigned short h[8]; i32x4 v; } o;
  o.h[0] = f2bf(a.x); o.h[1] = f2bf(a.y); o.h[2] = f2bf(a.z); o.h[3] = f2bf(a.w);
  o.h[4] = f2bf(b.x); o.h[5] = f2bf(b.y); o.h[6] = f2bf(b.z); o.h[7] = f2bf(b.w);
  ((i32x4*)dst)[i] = o.v;
}

// src [E][Kdim][Ndim] f32  ->  pretile [e][ntile][ktile][chunk(0..31)][lane(0..63)][8] bf16
// chunk = nf_local*2 + ks ; element: n = ntile*256 + (chunk>>1)*16 + (lane&15)
//                           k = ktile*64 + (chunk&1)*32 + (lane>>4)*8 + i
__global__ void pretile_b(const float* __restrict__ src, unsigned short* __restrict__ dst,
                          int Kdim, int Ndim) {
  long long t = (long long)blockIdx.x * 256 + threadIdx.x;
  int lane = (int)(t & 63); long long rest = t >> 6;
  int chunk = (int)(rest & 31); rest >>= 5;
  int KT = Kdim >> 6;
  int ktile = (int)(rest % KT); rest /= KT;
  int NT = Ndim >> 8;
  int ntile = (int)(rest % NT); int e = (int)(rest / NT);
  int n = (ntile << 8) + ((chunk >> 1) << 4) + (lane & 15);
  int k = (ktile << 6) + ((chunk & 1) << 5) + ((lane >> 4) << 3);
  const float* s = src + ((size_t)e * Kdim + k) * Ndim + n;
  union { unsigned short h[8]; i32x4 v; } o;
#pragma unroll
  for (int i = 0; i < 8; ++i) o.h[i] = f2bf(s[(size_t)i * Ndim]);
  ((i32x4*)dst)[t] = o.v;
}

// ---------------- GEMM: 256x256, BK=64, 8 waves, bulk-sync phases, counted vmcnt ----
// A: row-major XOR-swizzled LDS (conflict-free, proven). B: fragment-major pretile.

#define PHASE_MFMA(MA, MB, A0, A1, A2, A3)                                                  \
  do {                                                                                      \
    __builtin_amdgcn_s_setprio(1);                                                          \
    _Pragma("unroll") for (int n = 0; n < 4; ++n)                                           \
        acc[MA][n] = __builtin_amdgcn_mfma_f32_16x16x32_bf16(A0, bg0[n], acc[MA][n], 0, 0, 0); \
    _Pragma("unroll") for (int n = 0; n < 4; ++n)                                           \
        acc[MB][n] = __builtin_amdgcn_mfma_f32_16x16x32_bf16(A2, bg0[n], acc[MB][n], 0, 0, 0); \
    _Pragma("unroll") for (int n = 0; n < 4; ++n)                                           \
        acc[MA][n] = __builtin_amdgcn_mfma_f32_16x16x32_bf16(A1, bg1[n], acc[MA][n], 0, 0, 0); \
    _Pragma("unroll") for (int n = 0; n < 4; ++n)                                           \
        acc[MB][n] = __builtin_amdgcn_mfma_f32_16x16x32_bf16(A3, bg1[n], acc[MB][n], 0, 0, 0); \
    __builtin_amdgcn_s_setprio(0);                                                          \
  } while (0)

template <int MODE>
__global__ __launch_bounds__(512, 2) void moe_gemm(
    const unsigned short* __restrict__ Abase,
    const unsigned short* __restrict__ Bpre,   // fragment-major pretile
    const float* __restrict__ bias,
    const int* __restrict__ meta,
    const int* __restrict__ etok,
    const float* __restrict__ ewgt,
    unsigned short* __restrict__ Hbuf,
    float* __restrict__ Out,
    int Astride, int BtNT, int BtKT,
    int nbase, int kbase, int Klen,
    int biasStride, int Hstride, int addbias) {
  const int* offsets = meta + 16;
  int ntiles = meta[48];
  int NX = gridDim.x;
  int lid = blockIdx.x + NX * blockIdx.y;
  int Ntot = NX * ntiles;
  if (lid >= Ntot) return;
  int q = Ntot >> 3, r = Ntot & 7;
  int xcd = lid & 7, pos = lid >> 3;
  int nlid = (xcd < r ? xcd * (q + 1) : r * (q + 1) + (xcd - r) * q) + pos;
  int nt = nlid / ntiles;
  int mti = nlid - nt * ntiles;
  int te = meta[64 + mti];
  int e = te & 255, mt = te >> 8;
  int off = offsets[e], cnt = offsets[e + 1] - off;
  int total = offsets[NEXP];

  // A region [0,64K): 2 K-tile slots x (2 halves x 16KiB). B region [64K,128K): same.
  __shared__ __align__(128) char lds[131072];

  int tid = threadIdx.x;
  int lane = tid & 63, wid = tid >> 6;
  int wr = wid >> 2, wc = wid & 3;
  int fr = lane & 15, fu = lane >> 4;
  int cu0 = fu ^ (fr & 7);

  // ---- A staging sources (row-major, pre-swizzled source unit) ----
  int rg = (lane >> 3) & 7;
  int g = (lane & 7) ^ rg;
  const char* srcA[2][2];
#pragma unroll
  for (int h = 0; h < 2; ++h) {
#pragma unroll
    for (int j = 0; j < 2; ++j) {
      int rA = wid * 16 + j * 8 + rg;
      int gi = off + mt * 256 + h * 128 + rA;
      if (MODE == 0) {
        if (gi > total - 1) gi = total - 1;
        srcA[h][j] = (const char*)(Abase + (size_t)etok[gi] * Astride) + g * 16;
      } else {
        if (gi > MAXENT - 1) gi = MAXENT - 1;
        srcA[h][j] = (const char*)(Abase + (size_t)gi * Astride) + g * 16;
      }
    }
  }
  // ---- B staging sources (pretile: perfectly linear per wave) ----
  const char* srcB[2][2];
  {
    const char* BpreE = (const char*)Bpre +
        ((((size_t)e * BtNT + (nbase >> 8) + nt) * BtKT + (kbase >> 6)) << 15);
#pragma unroll
    for (int h = 0; h < 2; ++h)
#pragma unroll
      for (int j = 0; j < 2; ++j)
        srcB[h][j] = BpreE + (h << 14) + ((j * 8 + wid) << 10) + (lane << 4);
  }

#define STA(Tn, h) do { \
    char* _d = lds + (((Tn) & 1) << 15) + ((h) << 14) + wid * 2048; \
    gload16(srcA[h][0] + ((size_t)(Tn) << 7), _d); \
    gload16(srcA[h][1] + ((size_t)(Tn) << 7), _d + 1024); } while (0)
#define STB(Tn, h) do { \
    char* _d = lds + 65536 + (((Tn) & 1) << 15) + ((h) << 14) + (wid << 10); \
    gload16(srcB[h][0] + ((size_t)(Tn) << 15), _d); \
    gload16(srcB[h][1] + ((size_t)(Tn) << 15), _d + 8192); } while (0)

  f32x4 acc[8][4];
#pragma unroll
  for (int m = 0; m < 8; ++m)
#pragma unroll
    for (int n = 0; n < 4; ++n) acc[m][n] = (f32x4){0.f, 0.f, 0.f, 0.f};

  int nk = Klen >> 6;

  STA(0, 0); STA(0, 1); STB(0, 0); STB(0, 1); STB(1, 0); STB(1, 1);
  VMWAIT(4);
  bar();

  for (int T = 0; T < nk; ++T) {
    const char* sA = lds + ((T & 1) << 15) + (wr << 14);
    const char* pa0 = sA + fr * 128 + cu0 * 16;
    const char* pa1 = sA + fr * 128 + (cu0 ^ 4) * 16;
    const char* pb = lds + 65536 + ((T & 1) << 15) + (wc << 13) + (lane << 4);
    bool s1 = (T + 1 < nk), s2 = (T + 2 < nk);

    // ---- phase 0: bg(all) + a(m0,m1) reads; stage A(T+1,h0) ----
    bf16x8 bg0[4], bg1[4];
#pragma unroll
    for (int n = 0; n < 4; ++n) {
      bg0[n] = *(const bf16x8*)(pb + n * 2048);
      bg1[n] = *(const bf16x8*)(pb + n * 2048 + 1024);
    }
    bf16x8 a0 = *(const bf16x8*)(pa0);
    bf16x8 a1 = *(const bf16x8*)(pa1);
    bf16x8 a2 = *(const bf16x8*)(pa0 + 2048);
    bf16x8 a3 = *(const bf16x8*)(pa1 + 2048);
    if (s1) STA(T + 1, 0);
    bar();
    PHASE_MFMA(0, 1, a0, a1, a2, a3);
    bar();

    // ---- phase 1: a(m2,m3); stage A(T+1,h1) ----
    a0 = *(const bf16x8*)(pa0 + 4096);
    a1 = *(const bf16x8*)(pa1 + 4096);
    a2 = *(const bf16x8*)(pa0 + 6144);
    a3 = *(const bf16x8*)(pa1 + 6144);
    if (s1) STA(T + 1, 1);
    bar();
    PHASE_MFMA(2, 3, a0, a1, a2, a3);
    bar();

    // ---- phase 2: a(m4,m5); stage B(T+2,h0) ----
    a0 = *(const bf16x8*)(pa0 + 8192);
    a1 = *(const bf16x8*)(pa1 + 8192);
    a2 = *(const bf16x8*)(pa0 + 10240);
    a3 = *(const bf16x8*)(pa1 + 10240);
    if (s2) STB(T + 2, 0);
    bar();
    PHASE_MFMA(4, 5, a0, a1, a2, a3);
    bar();

    // ---- phase 3: a(m6,m7); stage B(T+2,h1); counted drain ----
    a0 = *(const bf16x8*)(pa0 + 12288);
    a1 = *(const bf16x8*)(pa1 + 12288);
    a2 = *(const bf16x8*)(pa0 + 14336);
    a3 = *(const bf16x8*)(pa1 + 14336);
    if (s2) STB(T + 2, 1);
    if (s2) { VMWAIT(4); }
    else if (s1) { VMWAIT(0); }
    bar();
    PHASE_MFMA(6, 7, a0, a1, a2, a3);
    bar();
  }
#undef STA
#undef STB

  int colb = nt * 256 + wc * 64;
  if (MODE == 0) {
#pragma unroll
    for (int m = 0; m < 8; ++m) {
#pragma unroll
      for (int r = 0; r < 4; ++r) {
        int row = wr * 128 + m * 16 + fu * 4 + r;
        int gm = mt * 256 + row;
        if (gm < cnt) {
          size_t hrow = (size_t)(off + gm) * Hstride;
#pragma unroll
          for (int n = 0; n < 4; ++n) {
            int col = colb + n * 16 + fr;
            float v = acc[m][n][r] + bias[e * biasStride + nbase + col];
            v = v / (1.f + __expf(-v));
            Hbuf[hrow + col] = f2bf(v);
          }
        }
      }
    }
  } else {
#pragma unroll
    for (int m = 0; m < 8; ++m) {
#pragma unroll
      for (int r = 0; r < 4; ++r) {
        int row = wr * 128 + m * 16 + fu * 4 + r;
        int gm = mt * 256 + row;
        if (gm < cnt) {
          int ent = off + gm;
          int tok = etok[ent];
          float wgt = ewgt[ent];
#pragma unroll
          for (int n = 0; n < 4; ++n) {
            int col = colb + n * 16 + fr;
            float v = acc[m][n][r];
            if (addbias) v += bias[e * biasStride + col];
            atomicAdd(Out + (size_t)tok * DDIM + col, v * wgt);
          }
        }
      }
    }
  }
}

// ---------------- host launch ----------------

extern "C" void kernel_launch(void* const* d_in, const int* in_sizes, int n_in,
                              void* d_out, int out_size, void* d_ws, size_t ws_size,
                              hipStream_t stream) {
  (void)in_sizes; (void)n_in;
  const float* x = (const float*)d_in[0];
  const int* eidx = (const int*)d_in[1];
  const float* ew = (const float*)d_in[2];
  const float* w1 = (const float*)d_in[3];
  const float* b1 = (const float*)d_in[4];
  const float* w2 = (const float*)d_in[5];
  const float* b2 = (const float*)d_in[6];
  float* out = (float*)d_out;

  char* w = (char*)d_ws;
  size_t o_meta = 0;
  size_t o_etok = 4096;
  size_t o_ewgt = o_etok + (size_t)MAXENT * 4;
  size_t o_x    = o_ewgt + (size_t)MAXENT * 4;
  size_t o_w1t  = o_x + (size_t)TOKENS * DDIM * 2;
  size_t o_w2t  = o_w1t + (size_t)DDIM * HDIM * NEXP * 2;
  size_t o_h    = o_w2t + (size_t)DDIM * HDIM * NEXP * 2;

  int S = 1;
  while (S < 16) {
    size_t need = o_h + (size_t)MAXENT * (HDIM / S) * 2;
    if (need <= ws_size) break;
    S *= 2;
  }
  int HC = HDIM / S;

  int* meta = (int*)(w + o_meta);
  int* etok = (int*)(w + o_etok);
  float* ewgt = (float*)(w + o_ewgt);
  unsigned short* xb = (unsigned short*)(w + o_x);
  unsigned short* w1t = (unsigned short*)(w + o_w1t);
  unsigned short* w2t = (unsigned short*)(w + o_w2t);
  unsigned short* hbuf = (unsigned short*)(w + o_h);

  hipMemsetAsync(w + o_meta, 0, 4096, stream);
  hipMemsetAsync(d_out, 0, (size_t)out_size * 4, stream);

  moe_count<<<TOKENS / 256, 256, 0, stream>>>(eidx, meta);
  moe_scan<<<1, 64, 0, stream>>>(meta);
  moe_scatter<<<TOKENS / 256, 256, 0, stream>>>(eidx, ew, meta, etok, ewgt);
  cvt_x_bf16<<<(TOKENS * DDIM / 8 + 255) / 256, 256, 0, stream>>>(x, xb, TOKENS * DDIM / 8);
  // w1: Kdim=DDIM, Ndim=HDIM ; w2: Kdim=HDIM, Ndim=DDIM
  {
    long long pieces = (long long)NEXP * (HDIM >> 8) * (DDIM >> 6) * 32 * 64;
    pretile_b<<<(int)(pieces / 256), 256, 0, stream>>>(w1, w1t, DDIM, HDIM);
    long long pieces2 = (long long)NEXP * (DDIM >> 8) * (HDIM >> 6) * 32 * 64;
    pretile_b<<<(int)(pieces2 / 256), 256, 0, stream>>>(w2, w2t, HDIM, DDIM);
  }

  for (int s = 0; s < S; ++s) {
    moe_gemm<0><<<dim3(HC / 256, MAXTILES, 1), 512, 0, stream>>>(
        xb, w1t, b1, meta, etok, ewgt, hbuf, nullptr,
        DDIM, HDIM / 256, DDIM / 64, s * HC, 0, DDIM, HDIM, HC, 0);
    moe_gemm<1><<<dim3(DDIM / 256, MAXTILES, 1), 512, 0, stream>>>(
        hbuf, w2t, b2, meta, etok, ewgt, nullptr, out,
        HC, DDIM / 256, HDIM / 64, 0, s * HC, HC, DDIM, 0, (s == 0) ? 1 : 0);
  }
}

// Round 5
// 582.272 us; speedup vs baseline: 1.3829x; 1.0153x over previous
//
#include <hip/hip_runtime.h>
#include <hip/hip_bf16.h>
#include <stdint.h>

#define TOKENS 8192
#define DDIM 1024
#define HDIM 4096
#define NEXP 8
#define MAXENT 16384
#define MAXTILES 72

typedef __attribute__((ext_vector_type(4))) float f32x4;
typedef __attribute__((ext_vector_type(8))) short bf16x8;
typedef __attribute__((ext_vector_type(4))) int i32x4;

__device__ __forceinline__ unsigned short f2bf(float f) {
  __hip_bfloat16 h = __float2bfloat16(f);
  return __builtin_bit_cast(unsigned short, h);
}

__device__ __forceinline__ void gload16(const void* g, void* l) {
  __builtin_amdgcn_global_load_lds(
      (const __attribute__((address_space(1))) unsigned int*)g,
      (__attribute__((address_space(3))) unsigned int*)l, 16, 0, 0);
}

__device__ __forceinline__ void bar() {
  asm volatile("" ::: "memory");
  __builtin_amdgcn_sched_barrier(0);
  __builtin_amdgcn_s_barrier();
  __builtin_amdgcn_sched_barrier(0);
  asm volatile("" ::: "memory");
}

#define VMWAIT(N) asm volatile("s_waitcnt vmcnt(" #N ")" ::: "memory")

// ---------------- prep ----------------

__global__ void moe_count(const int* __restrict__ idx, int* __restrict__ meta) {
  int t = blockIdx.x * 256 + threadIdx.x;
  if (t >= TOKENS) return;
  int e0 = idx[2 * t], e1 = idx[2 * t + 1];
  atomicAdd(&meta[e0], 1);
  if (e1 != e0) atomicAdd(&meta[e1], 1);
}

__global__ void moe_scan(int* __restrict__ meta) {
  if (threadIdx.x != 0 || blockIdx.x != 0) return;
  int s = 0;
  for (int e = 0; e < NEXP; ++e) { meta[16 + e] = s; meta[32 + e] = s; s += meta[e]; }
  meta[16 + NEXP] = s;
  int nt = 0;
  for (int e = 0; e < NEXP; ++e) {
    int m = (meta[e] + 255) >> 8;
    for (int t = 0; t < m; ++t) meta[64 + nt++] = e | (t << 8);
  }
  meta[48] = nt;
}

__global__ void moe_scatter(const int* __restrict__ idx, const float* __restrict__ ew,
                            int* __restrict__ meta, int* __restrict__ etok,
                            float* __restrict__ ewgt) {
  int t = blockIdx.x * 256 + threadIdx.x;
  if (t >= TOKENS) return;
  int e0 = idx[2 * t], e1 = idx[2 * t + 1];
  float a = ew[2 * t], b = ew[2 * t + 1];
  if (e0 == e1) {
    int p = atomicAdd(&meta[32 + e0], 1);
    etok[p] = t; ewgt[p] = a + b;
  } else {
    int p = atomicAdd(&meta[32 + e0], 1);
    etok[p] = t; ewgt[p] = a;
    int q = atomicAdd(&meta[32 + e1], 1);
    etok[q] = t; ewgt[q] = b;
  }
}

// ---------------- conversions ----------------

__global__ void cvt_x_bf16(const float* __restrict__ src, unsigned short* __restrict__ dst, int n8) {
  int i = blockIdx.x * 256 + threadIdx.x;
  if (i >= n8) return;
  const float4* s4 = (const float4*)src;
  float4 a = s4[2 * i], b = s4[2 * i + 1];
  union { unsigned short h[8]; i32x4 v; } o;
  o.h[0] = f2bf(a.x); o.h[1] = f2bf(a.y); o.h[2] = f2bf(a.z); o.h[3] = f2bf(a.w);
  o.h[4] = f2bf(b.x); o.h[5] = f2bf(b.y); o.h[6] = f2bf(b.z); o.h[7] = f2bf(b.w);
  ((i32x4*)dst)[i] = o.v;
}

// src [E][Kdim][Ndim] f32  ->  pretile [e][ntile][ktile][chunk(0..31)][lane(0..63)][8] bf16
__global__ void pretile_b(const float* __restrict__ src, unsigned short* __restrict__ dst,
                          int Kdim, int Ndim) {
  long long t = (long long)blockIdx.x * 256 + threadIdx.x;
  int lane = (int)(t & 63); long long rest = t >> 6;
  int chunk = (int)(rest & 31); rest >>= 5;
  int KT = Kdim >> 6;
  int ktile = (int)(rest % KT); rest /= KT;
  int NT = Ndim >> 8;
  int ntile = (int)(rest % NT); int e = (int)(rest / NT);
  int n = (ntile << 8) + ((chunk >> 1) << 4) + (lane & 15);
  int k = (ktile << 6) + ((chunk & 1) << 5) + ((lane >> 4) << 3);
  const float* s = src + ((size_t)e * Kdim + k) * Ndim + n;
  union { unsigned short h[8]; i32x4 v; } o;
#pragma unroll
  for (int i = 0; i < 8; ++i) o.h[i] = f2bf(s[(size_t)i * Ndim]);
  ((i32x4*)dst)[t] = o.v;
}

// ---- GEMM: 256x256, BK=64, 8 waves, 1 barrier/K-tile, read-ahead pipeline ----
// A: 2-slot ring (row-major XOR-swizzled). B: 3-slot ring (fragment-major pretile).
// LDS = 64K + 96K = 160 KiB (full pool, 1 block/CU).

#define MF(P, A0, A1, A2, A3)                                                                  \
  do {                                                                                         \
    __builtin_amdgcn_s_setprio(1);                                                             \
    _Pragma("unroll") for (int n = 0; n < 4; ++n)                                              \
        acc[2*(P)][n]   = __builtin_amdgcn_mfma_f32_16x16x32_bf16(A0, bg0[n], acc[2*(P)][n], 0, 0, 0); \
    _Pragma("unroll") for (int n = 0; n < 4; ++n)                                              \
        acc[2*(P)+1][n] = __builtin_amdgcn_mfma_f32_16x16x32_bf16(A2, bg0[n], acc[2*(P)+1][n], 0, 0, 0); \
    _Pragma("unroll") for (int n = 0; n < 4; ++n)                                              \
        acc[2*(P)][n]   = __builtin_amdgcn_mfma_f32_16x16x32_bf16(A1, bg1[n], acc[2*(P)][n], 0, 0, 0); \
    _Pragma("unroll") for (int n = 0; n < 4; ++n)                                              \
        acc[2*(P)+1][n] = __builtin_amdgcn_mfma_f32_16x16x32_bf16(A3, bg1[n], acc[2*(P)+1][n], 0, 0, 0); \
    __builtin_amdgcn_s_setprio(0);                                                             \
  } while (0)

template <int MODE>
__global__ __launch_bounds__(512, 2) void moe_gemm(
    const unsigned short* __restrict__ Abase,
    const unsigned short* __restrict__ Bpre,
    const float* __restrict__ bias,
    const int* __restrict__ meta,
    const int* __restrict__ etok,
    const float* __restrict__ ewgt,
    unsigned short* __restrict__ Hbuf,
    float* __restrict__ Out,
    int Astride, int BtNT, int BtKT,
    int nbase, int kbase, int Klen,
    int biasStride, int Hstride, int addbias) {
  const int* offsets = meta + 16;
  int ntiles = meta[48];
  int NX = gridDim.x;
  int lid = blockIdx.x + NX * blockIdx.y;
  int Ntot = NX * ntiles;
  if (lid >= Ntot) return;
  int q = Ntot >> 3, r = Ntot & 7;
  int xcd = lid & 7, pos = lid >> 3;
  int nlid = (xcd < r ? xcd * (q + 1) : r * (q + 1) + (xcd - r) * q) + pos;
  int nt = nlid / ntiles;
  int mti = nlid - nt * ntiles;
  int te = meta[64 + mti];
  int e = te & 255, mt = te >> 8;
  int off = offsets[e], cnt = offsets[e + 1] - off;
  int total = offsets[NEXP];

  // A: [0,64K) 2 slots x 32 KiB. B: [64K,160K) 3 slots x 32 KiB.
  __shared__ __align__(128) char lds[163840];

  int tid = threadIdx.x;
  int lane = tid & 63, wid = tid >> 6;
  int wr = wid >> 2, wc = wid & 3;
  int fr = lane & 15, fu = lane >> 4;
  int cu0 = fu ^ (fr & 7);

  // ---- A staging sources ----
  int rg = (lane >> 3) & 7;
  int g = (lane & 7) ^ rg;
  const char* srcA[2][2];
#pragma unroll
  for (int h = 0; h < 2; ++h) {
#pragma unroll
    for (int j = 0; j < 2; ++j) {
      int rA = wid * 16 + j * 8 + rg;
      int gi = off + mt * 256 + h * 128 + rA;
      if (MODE == 0) {
        if (gi > total - 1) gi = total - 1;
        srcA[h][j] = (const char*)(Abase + (size_t)etok[gi] * Astride) + g * 16;
      } else {
        if (gi > MAXENT - 1) gi = MAXENT - 1;
        srcA[h][j] = (const char*)(Abase + (size_t)gi * Astride) + g * 16;
      }
    }
  }
  // ---- B staging sources (pretile: linear per wave) ----
  const char* srcB[2][2];
  {
    const char* BpreE = (const char*)Bpre +
        ((((size_t)e * BtNT + (nbase >> 8) + nt) * BtKT + (kbase >> 6)) << 15);
#pragma unroll
    for (int h = 0; h < 2; ++h)
#pragma unroll
      for (int j = 0; j < 2; ++j)
        srcB[h][j] = BpreE + (h << 14) + ((j * 8 + wid) << 10) + (lane << 4);
  }

#define STA(Tn, h) do { \
    char* _d = lds + (((Tn) & 1) << 15) + ((h) << 14) + (wid << 11); \
    gload16(srcA[h][0] + ((size_t)(Tn) << 7), _d); \
    gload16(srcA[h][1] + ((size_t)(Tn) << 7), _d + 1024); } while (0)
#define STB(sl, Tn, h) do { \
    char* _d = lds + 65536 + ((sl) * 32768) + ((h) << 14) + (wid << 10); \
    gload16(srcB[h][0] + ((size_t)(Tn) << 15), _d); \
    gload16(srcB[h][1] + ((size_t)(Tn) << 15), _d + 8192); } while (0)

  f32x4 acc[8][4];
#pragma unroll
  for (int m = 0; m < 8; ++m)
#pragma unroll
    for (int n = 0; n < 4; ++n) acc[m][n] = (f32x4){0.f, 0.f, 0.f, 0.f};

  bf16x8 bg0[4], bg1[4];
  auto rdA = [&](int T, int p, bf16x8& x0, bf16x8& x1, bf16x8& x2, bf16x8& x3) {
    const char* b = lds + ((T & 1) << 15) + (wr << 14) + fr * 128;
    const char* p0 = b + cu0 * 16;
    const char* p1 = b + (cu0 ^ 4) * 16;
    x0 = *(const bf16x8*)(p0 + (2 * p) * 2048);
    x1 = *(const bf16x8*)(p1 + (2 * p) * 2048);
    x2 = *(const bf16x8*)(p0 + (2 * p + 1) * 2048);
    x3 = *(const bf16x8*)(p1 + (2 * p + 1) * 2048);
  };
  auto rdB = [&](int sl) {
    const char* pb = lds + 65536 + sl * 32768 + (wc << 13) + (lane << 4);
#pragma unroll
    for (int n = 0; n < 4; ++n) {
      bg0[n] = *(const bf16x8*)(pb + n * 2048);
      bg1[n] = *(const bf16x8*)(pb + n * 2048 + 1024);
    }
  };

  int nk = Klen >> 6;

  // prologue: A(0), B(0)->slot0, B(1)->slot1
  STA(0, 0); STA(0, 1);
  STB(0, 0, 0); STB(0, 0, 1);
  STB(1, 1, 0); STB(1, 1, 1);
  VMWAIT(4);
  bar();

  bf16x8 c0, c1, c2, c3, n0, n1, n2, n3;
  rdA(0, 0, c0, c1, c2, c3);
  rdB(0);

  int bs = 0;  // slot holding B(T)
  for (int T = 0; T < nk; ++T) {
    int s1 = (T + 1 < nk), s2 = (T + 2 < nk);
    // ph0: read A(T,m2m3); stage A(T+1,h0); MFMA m0,m1
    rdA(T, 1, n0, n1, n2, n3);
    if (s1) STA(T + 1, 0);
    MF(0, c0, c1, c2, c3);
    // ph1: read A(T,m4m5); stage A(T+1,h1); MFMA m2,m3
    rdA(T, 2, c0, c1, c2, c3);
    if (s1) STA(T + 1, 1);
    MF(1, n0, n1, n2, n3);
    // ph2: read A(T,m6m7); stage B(T+2) -> slot (bs+2)%3; MFMA m4,m5
    rdA(T, 3, n0, n1, n2, n3);
    int bs2 = bs >= 1 ? bs - 1 : bs + 2;
    if (s2) { STB(bs2, T + 2, 0); STB(bs2, T + 2, 1); }
    MF(2, c0, c1, c2, c3);
    // ph3: MFMA m6,m7; counted drain; barrier; read-ahead tile T+1
    MF(3, n0, n1, n2, n3);
    if (s2) { VMWAIT(4); } else if (s1) { VMWAIT(0); }
    bar();
    int Tn = s1 ? T + 1 : T;
    int bsn = bs < 2 ? bs + 1 : 0;
    rdA(Tn, 0, c0, c1, c2, c3);
    rdB(s1 ? bsn : bs);
    bs = bsn;
  }
#undef STA
#undef STB

  int colb = nt * 256 + wc * 64;
  if (MODE == 0) {
#pragma unroll
    for (int m = 0; m < 8; ++m) {
#pragma unroll
      for (int r = 0; r < 4; ++r) {
        int row = wr * 128 + m * 16 + fu * 4 + r;
        int gm = mt * 256 + row;
        if (gm < cnt) {
          size_t hrow = (size_t)(off + gm) * Hstride;
#pragma unroll
          for (int n = 0; n < 4; ++n) {
            int col = colb + n * 16 + fr;
            float v = acc[m][n][r] + bias[e * biasStride + nbase + col];
            v = v / (1.f + __expf(-v));
            Hbuf[hrow + col] = f2bf(v);
          }
        }
      }
    }
  } else {
#pragma unroll
    for (int m = 0; m < 8; ++m) {
#pragma unroll
      for (int r = 0; r < 4; ++r) {
        int row = wr * 128 + m * 16 + fu * 4 + r;
        int gm = mt * 256 + row;
        if (gm < cnt) {
          int ent = off + gm;
          int tok = etok[ent];
          float wgt = ewgt[ent];
#pragma unroll
          for (int n = 0; n < 4; ++n) {
            int col = colb + n * 16 + fr;
            float v = acc[m][n][r];
            if (addbias) v += bias[e * biasStride + col];
            atomicAdd(Out + (size_t)tok * DDIM + col, v * wgt);
          }
        }
      }
    }
  }
}

// ---------------- host launch ----------------

extern "C" void kernel_launch(void* const* d_in, const int* in_sizes, int n_in,
                              void* d_out, int out_size, void* d_ws, size_t ws_size,
                              hipStream_t stream) {
  (void)in_sizes; (void)n_in;
  const float* x = (const float*)d_in[0];
  const int* eidx = (const int*)d_in[1];
  const float* ew = (const float*)d_in[2];
  const float* w1 = (const float*)d_in[3];
  const float* b1 = (const float*)d_in[4];
  const float* w2 = (const float*)d_in[5];
  const float* b2 = (const float*)d_in[6];
  float* out = (float*)d_out;

  char* w = (char*)d_ws;
  size_t o_meta = 0;
  size_t o_etok = 4096;
  size_t o_ewgt = o_etok + (size_t)MAXENT * 4;
  size_t o_x    = o_ewgt + (size_t)MAXENT * 4;
  size_t o_w1t  = o_x + (size_t)TOKENS * DDIM * 2;
  size_t o_w2t  = o_w1t + (size_t)DDIM * HDIM * NEXP * 2;
  size_t o_h    = o_w2t + (size_t)DDIM * HDIM * NEXP * 2;

  int S = 1;
  while (S < 16) {
    size_t need = o_h + (size_t)MAXENT * (HDIM / S) * 2;
    if (need <= ws_size) break;
    S *= 2;
  }
  int HC = HDIM / S;

  int* meta = (int*)(w + o_meta);
  int* etok = (int*)(w + o_etok);
  float* ewgt = (float*)(w + o_ewgt);
  unsigned short* xb = (unsigned short*)(w + o_x);
  unsigned short* w1t = (unsigned short*)(w + o_w1t);
  unsigned short* w2t = (unsigned short*)(w + o_w2t);
  unsigned short* hbuf = (unsigned short*)(w + o_h);

  hipMemsetAsync(w + o_meta, 0, 4096, stream);
  hipMemsetAsync(d_out, 0, (size_t)out_size * 4, stream);

  moe_count<<<TOKENS / 256, 256, 0, stream>>>(eidx, meta);
  moe_scan<<<1, 64, 0, stream>>>(meta);
  moe_scatter<<<TOKENS / 256, 256, 0, stream>>>(eidx, ew, meta, etok, ewgt);
  cvt_x_bf16<<<(TOKENS * DDIM / 8 + 255) / 256, 256, 0, stream>>>(x, xb, TOKENS * DDIM / 8);
  {
    long long pieces = (long long)NEXP * (HDIM >> 8) * (DDIM >> 6) * 32 * 64;
    pretile_b<<<(int)(pieces / 256), 256, 0, stream>>>(w1, w1t, DDIM, HDIM);
    long long pieces2 = (long long)NEXP * (DDIM >> 8) * (HDIM >> 6) * 32 * 64;
    pretile_b<<<(int)(pieces2 / 256), 256, 0, stream>>>(w2, w2t, HDIM, DDIM);
  }

  for (int s = 0; s < S; ++s) {
    moe_gemm<0><<<dim3(HC / 256, MAXTILES, 1), 512, 0, stream>>>(
        xb, w1t, b1, meta, etok, ewgt, hbuf, nullptr,
        DDIM, HDIM / 256, DDIM / 64, s * HC, 0, DDIM, HDIM, HC, 0);
    moe_gemm<1><<<dim3(DDIM / 256, MAXTILES, 1), 512, 0, stream>>>(
        hbuf, w2t, b2, meta, etok, ewgt, nullptr, out,
        HC, DDIM / 256, HDIM / 64, 0, s * HC, HC, DDIM, 0, (s == 0) ? 1 : 0);
  }
}